// Round 6
// baseline (293.792 us; speedup 1.0000x reference)
//
#include <hip/hip_runtime.h>
#include <hip/hip_bf16.h>

#define BB 64
#define AA 8732
#define GG 50
#define CC 81
#define NEG_RATIO 3
#define HW 16          // waves per k_hardneg block
#define HSTRIDE 257    // padded per-wave histogram stride
#define NCHUNK 137     // ceil(AA/64)
#define XB 32          // k_match blocks per batch

// ws layout (float offsets):
//   acc_slots[2048] @0            (float, one per k_match block)
//   np_slots[2048]  @2048         (int,   one per k_match block)
//   hn_accum        @4096         (float)
//   counter         @4097         (int)
//   conf            @8192         (BB*AA floats)
//   conf_neg        @8192+BB*AA

__device__ __forceinline__ unsigned mono_key(float f) {
    unsigned u = __float_as_uint(f);
    u = (u & 0x80000000u) ? ~u : (u | 0x80000000u);  // ascending float -> ascending uint
    return ~u;                                        // ascending key == descending float
}

// Grid-stride, software-pipelined, atomic-free.
__global__ __launch_bounds__(256, 4) void k_match(
    const float* __restrict__ pred_boxes, const float* __restrict__ pred_scores,
    const float* __restrict__ gt_boxes, const int* __restrict__ gt_labels,
    float* __restrict__ conf_out, float* __restrict__ confneg_out,
    float* __restrict__ acc_slots, int* __restrict__ np_slots,
    float* __restrict__ hn_accum, int* __restrict__ counter)
{
    __shared__ float4 sgt[GG];
    __shared__ float  sarea[GG];
    __shared__ int    slab[GG];
    __shared__ float  redf[4];
    __shared__ int    redi[4];

    const int tid = threadIdx.x;
    const int b = blockIdx.y;
    const int x = blockIdx.x;          // 0..XB-1
    const int grp = tid >> 2;          // anchor-in-chunk
    const int q   = tid & 3;           // lane within 4-lane group

    if (b == 0 && x == 0 && tid == 0) { *counter = 0; *hn_accum = 0.f; }  // visible at kernel end

    if (tid < GG) {
        const float* gp = gt_boxes + ((size_t)b * GG + tid) * 4;
        float4 g4 = make_float4(gp[0], gp[1], gp[2], gp[3]);
        sgt[tid] = g4;
        sarea[tid] = (g4.z - g4.x) * (g4.w - g4.y);
        slab[tid] = gt_labels[b * GG + tid];
    }
    __syncthreads();   // once per block

    const float*  sb = pred_scores + (size_t)b * AA * CC;
    const float4* bbx = (const float4*)pred_boxes + (size_t)b * AA;

    float contrib = 0.f;
    int npos = 0;

    // ---- prefetch first chunk ----
    int a0 = x * 64 + grp;
    int am = a0 < AA ? a0 : AA - 1;
    float4 nbox = bbx[am];
    const float* nrow = sb + (size_t)am * CC;
    float4 ns0 = *(const float4*)(nrow + 4 * q);
    float4 ns1 = *(const float4*)(nrow + 4 * q + 16);
    float4 ns2 = *(const float4*)(nrow + 4 * q + 32);
    float4 ns3 = *(const float4*)(nrow + 4 * q + 48);
    float4 ns4 = *(const float4*)(nrow + 4 * q + 64);
    float  ns80 = nrow[80];

    for (int c = x; c < NCHUNK; c += XB) {
        // rotate prefetched regs into current
        const float4 pb = nbox;
        const float4 s0 = ns0, s1 = ns1, s2 = ns2, s3 = ns3, s4 = ns4;
        const float  s80 = ns80;
        const int a = c * 64 + grp;
        const bool valid = a < AA;

        // prefetch next chunk (clamped; unconditional -> no spill-prone masks)
        int cn = c + XB; if (cn >= NCHUNK) cn = c;
        int an = cn * 64 + grp; if (an >= AA) an = AA - 1;
        nbox = bbx[an];
        const float* prow = sb + (size_t)an * CC;
        ns0 = *(const float4*)(prow + 4 * q);
        ns1 = *(const float4*)(prow + 4 * q + 16);
        ns2 = *(const float4*)(prow + 4 * q + 32);
        ns3 = *(const float4*)(prow + 4 * q + 48);
        ns4 = *(const float4*)(prow + 4 * q + 64);
        ns80 = prow[80];

        // ---- IoU argmax, 4-way split ----
        const float area_p = (pb.z - pb.x) * (pb.w - pb.y);
        float best = -1.f; int bidx = 0x7fffffff;
        for (int g = q; g < GG; g += 4) {
            float4 gb = sgt[g];
            float iw = fmaxf(fminf(pb.z, gb.z) - fmaxf(pb.x, gb.x), 0.f);
            float ih = fmaxf(fminf(pb.w, gb.w) - fmaxf(pb.y, gb.y), 0.f);
            float inter = iw * ih;
            float uni = fmaxf(area_p + sarea[g] - inter, 1e-6f);
            float iou = __fdividef(inter, uni);
            if (iou > best) { best = iou; bidx = g; }   // strict > keeps FIRST max in-lane
        }
        #pragma unroll
        for (int off = 1; off < 4; off <<= 1) {         // first-max merge: equal -> smaller idx
            float ov = __shfl_xor(best, off);
            int   oi = __shfl_xor(bidx, off);
            if (ov > best || (ov == best && oi < bidx)) { best = ov; bidx = oi; }
        }
        const int label = (best > 0.5f) ? slab[bidx] : 0;   // uniform across group

        // ---- softmax over 81 scores (lane q owns float4s f=q+4t) ----
        float sm = 0.f, labv = 0.f;
        {
            const float4 vv[5] = {s0, s1, s2, s3, s4};
            #pragma unroll
            for (int t = 0; t < 5; ++t) {
                const float4 v = vv[t];
                sm += __expf(v.x) + __expf(v.y) + __expf(v.z) + __expf(v.w);
                const int f = q + (t << 2);
                if ((label >> 2) == f) {
                    const int r = label & 3;
                    labv = (r == 0) ? v.x : (r == 1) ? v.y : (r == 2) ? v.z : v.w;
                }
            }
            if (q == 0) {
                sm += __expf(s80);
                if (label == 80) labv = s80;
            }
        }
        sm   += __shfl_xor(sm, 1);   sm   += __shfl_xor(sm, 2);
        labv += __shfl_xor(labv, 1); labv += __shfl_xor(labv, 2);  // one lane nonzero
        const float conf = __logf(sm) - labv;    // scores ~N(0,1): no max-shift needed

        if (q == 0 && valid) {
            const size_t ai = (size_t)b * AA + a;
            conf_out[ai] = conf;
            const bool pm = label > 0;
            confneg_out[ai] = pm ? -1.f : conf;
            if (pm) {
                npos++;
                const float4 gb = sgt[bidx];
                float sl1 = 0.f, d, ad;
                d = pb.x - gb.x; ad = fabsf(d); sl1 += (ad < 1.f) ? 0.5f * d * d : ad - 0.5f;
                d = pb.y - gb.y; ad = fabsf(d); sl1 += (ad < 1.f) ? 0.5f * d * d : ad - 0.5f;
                d = pb.z - gb.z; ad = fabsf(d); sl1 += (ad < 1.f) ? 0.5f * d * d : ad - 0.5f;
                d = pb.w - gb.w; ad = fabsf(d); sl1 += (ad < 1.f) ? 0.5f * d * d : ad - 0.5f;
                contrib += sl1 + conf;
            }
        }
    }

    // ---- block reduction -> per-block slot (no atomics) ----
    #pragma unroll
    for (int off = 32; off; off >>= 1) {
        contrib += __shfl_down(contrib, off);
        npos    += __shfl_down(npos, off);
    }
    const int wv = tid >> 6;
    if ((tid & 63) == 0) { redf[wv] = contrib; redi[wv] = npos; }
    __syncthreads();
    if (tid == 0) {
        acc_slots[b * XB + x] = redf[0] + redf[1] + redf[2] + redf[3];
        np_slots[b * XB + x]  = redi[0] + redi[1] + redi[2] + redi[3];
    }
}

// Per-batch hard-negative mining + fused final reduction (last-block pattern).
__global__ __launch_bounds__(1024) void k_hardneg(
    const float* __restrict__ confneg, const float* __restrict__ conf,
    const int* __restrict__ np_slots, const float* __restrict__ acc_slots,
    float* __restrict__ hn_accum, int* __restrict__ counter,
    float* __restrict__ out)
{
    __shared__ unsigned hist[HW * HSTRIDE];   // per-wave privatized
    __shared__ unsigned binsum[256];
    __shared__ unsigned sel[2];
    __shared__ unsigned uE[HW], uG[HW], eb[HW];
    __shared__ float    fred[HW];
    __shared__ int      ired[HW];
    __shared__ int      stot;
    __shared__ int      islast;

    const int b = blockIdx.x;
    const int tid = threadIdx.x;
    const int wv = tid >> 6;
    const int lane = tid & 63;

    int np = 0;
    #pragma unroll
    for (int i = 0; i < XB; ++i) np += np_slots[b * XB + i];
    int k = NEG_RATIO * np; if (k > AA - 1) k = AA - 1;

    float block_total = 0.f;
    if (k > 0) {                              // k is block-uniform
        const float* cn  = confneg + (size_t)b * AA;
        const float* cfp = conf    + (size_t)b * AA;

        // contiguous per-thread chunks preserve stable-by-index tie semantics
        const int lo = tid * 9;
        int nk = AA - lo; nk = nk > 9 ? 9 : (nk < 0 ? 0 : nk);
        unsigned keys[9]; float vals[9];
        #pragma unroll
        for (int j = 0; j < 9; ++j) {
            if (j < nk) { keys[j] = mono_key(cn[lo + j]); vals[j] = cfp[lo + j]; }
        }

        // ---- 4-level radix-256 select of k-th smallest key ----
        unsigned prefix = 0, kk = (unsigned)k;
        for (int lev = 0; lev < 4; ++lev) {
            const int shift = 24 - 8 * lev;
            for (int i = tid; i < HW * HSTRIDE; i += 1024) hist[i] = 0;
            __syncthreads();
            #pragma unroll
            for (int j = 0; j < 9; ++j) {
                if (j < nk) {
                    const unsigned key = keys[j];
                    if (lev == 0 || (key >> (shift + 8)) == prefix)
                        atomicAdd(&hist[wv * HSTRIDE + ((key >> shift) & 255u)], 1u);
                }
            }
            __syncthreads();
            if (tid < 256) {
                unsigned s = 0;
                #pragma unroll
                for (int w = 0; w < HW; ++w) s += hist[w * HSTRIDE + tid];
                binsum[tid] = s;
            }
            __syncthreads();
            if (wv == 0) {   // wave 0 scans 256 bins: 4 bins/lane + shfl scan
                const unsigned v0 = binsum[4 * lane], v1 = binsum[4 * lane + 1];
                const unsigned v2 = binsum[4 * lane + 2], v3 = binsum[4 * lane + 3];
                const unsigned lsum = v0 + v1 + v2 + v3;
                unsigned sc = lsum;
                #pragma unroll
                for (int off = 1; off < 64; off <<= 1) {
                    unsigned t = __shfl_up(sc, off);
                    if (lane >= off) sc += t;
                }
                const unsigned excl = sc - lsum;
                if (kk > excl && kk <= sc) {
                    unsigned cacc = excl;
                    if (kk <= cacc + v0)              { sel[0] = 4 * lane;     sel[1] = kk - cacc; }
                    else if (kk <= (cacc += v0) + v1) { sel[0] = 4 * lane + 1; sel[1] = kk - cacc; }
                    else if (kk <= (cacc += v1) + v2) { sel[0] = 4 * lane + 2; sel[1] = kk - cacc; }
                    else                              { sel[0] = 4 * lane + 3; sel[1] = kk - cacc - v2; }
                }
            }
            __syncthreads();
            prefix = (prefix << 8) | sel[0];
            kk = sel[1];
        }
        const unsigned kth = prefix;

        // ---- stable selection sum: key<kth all in; ==kth by ascending index ----
        int cntG = 0, cntE = 0; float sum_gt = 0.f;
        #pragma unroll
        for (int j = 0; j < 9; ++j) {
            if (j < nk) {
                if (keys[j] < kth)       { cntG++; sum_gt += vals[j]; }
                else if (keys[j] == kth) { cntE++; }
            }
        }
        int sc = cntE;
        #pragma unroll
        for (int off = 1; off < 64; off <<= 1) {
            int t = __shfl_up(sc, off);
            if (lane >= off) sc += t;
        }
        int gt = cntG;
        #pragma unroll
        for (int off = 32; off; off >>= 1) gt += __shfl_down(gt, off);
        if (lane == 63) uE[wv] = (unsigned)sc;
        if (lane == 0)  uG[wv] = (unsigned)gt;
        __syncthreads();
        if (wv == 0) {
            unsigned e = (lane < HW) ? uE[lane] : 0u;
            unsigned g = (lane < HW) ? uG[lane] : 0u;
            unsigned se = e;
            #pragma unroll
            for (int off = 1; off < 16; off <<= 1) {
                unsigned t = __shfl_up(se, off);
                if (lane >= off) se += t;
            }
            if (lane < HW) eb[lane] = se - e;
            #pragma unroll
            for (int off = 8; off; off >>= 1) g += __shfl_down(g, off);
            if (lane == 0) stot = (int)g;
        }
        __syncthreads();
        const int m = k - stot;                 // #ties to include, lowest indices first
        const int exclE = (int)eb[wv] + (sc - cntE);

        float sum_eq = 0.f;
        if (m > 0 && cntE > 0) {
            int seen = 0;
            #pragma unroll
            for (int j = 0; j < 9; ++j) {
                if (j < nk && keys[j] == kth) {
                    if (exclE + seen < m) sum_eq += vals[j];
                    seen++;
                }
            }
        }

        float contrib = sum_gt + sum_eq;
        #pragma unroll
        for (int off = 32; off; off >>= 1) contrib += __shfl_down(contrib, off);
        if (lane == 0) fred[wv] = contrib;
        __syncthreads();
        if (tid == 0) {
            float t = 0.f;
            #pragma unroll
            for (int w = 0; w < HW; ++w) t += fred[w];
            block_total = t;
        }
    }

    // ---- last-block protocol: publish contribution, detect completion ----
    if (tid == 0) {
        atomicAdd(hn_accum, block_total);   // device-scope
        __threadfence();
        int old = atomicAdd(counter, 1);
        islast = (old == BB - 1) ? 1 : 0;
    }
    __syncthreads();
    if (!islast) return;

    // ---- fused final reduction (this block saw all 64 contributions) ----
    float v = acc_slots[tid] + acc_slots[tid + 1024];   // 2048 k_match slots
    int den = 0;
    if (tid < BB) {
        int npb = 0;
        #pragma unroll
        for (int i = 0; i < XB; ++i) npb += np_slots[tid * XB + i];
        den = npb > 1 ? npb : 1;
    }
    #pragma unroll
    for (int off = 32; off; off >>= 1) {
        v   += __shfl_down(v, off);
        den += __shfl_down(den, off);
    }
    if (lane == 0) { fred[wv] = v; ired[wv] = den; }
    __syncthreads();
    if (tid == 0) {
        float num = 0.f; int d = 0;
        #pragma unroll
        for (int w = 0; w < HW; ++w) { num += fred[w]; d += ired[w]; }
        num += atomicAdd(hn_accum, 0.f);    // coherent read of the complete hard-neg sum
        out[0] = num / (float)d;
    }
}

extern "C" void kernel_launch(void* const* d_in, const int* in_sizes, int n_in,
                              void* d_out, int out_size, void* d_ws, size_t ws_size,
                              hipStream_t stream) {
    const float* pred_boxes  = (const float*)d_in[0];
    const float* pred_scores = (const float*)d_in[1];
    const float* gt_boxes    = (const float*)d_in[2];
    const int*   gt_labels   = (const int*)d_in[3];

    float* ws        = (float*)d_ws;
    float* acc_slots = ws;                    // 2048 floats
    int*   np_slots  = (int*)(ws + 2048);     // 2048 ints
    float* hn_accum  = ws + 4096;             // 1 float
    int*   counter   = (int*)(ws + 4097);     // 1 int
    float* conf      = ws + 8192;             // BB*AA floats
    float* conf_neg  = conf + (size_t)BB * AA;

    // no memset: counter/hn_accum zeroed by k_match; slots written before read

    dim3 g1(XB, BB);   // 32 x 64 blocks, grid-stride over 137 chunks of 64 anchors
    k_match<<<g1, 256, 0, stream>>>(pred_boxes, pred_scores, gt_boxes, gt_labels,
                                    conf, conf_neg, acc_slots, np_slots,
                                    hn_accum, counter);
    k_hardneg<<<BB, 1024, 0, stream>>>(conf_neg, conf, np_slots, acc_slots,
                                       hn_accum, counter, (float*)d_out);
}